// Round 2
// baseline (50.795 us; speedup 1.0000x reference)
//
#include <hip/hip_runtime.h>
#include <math.h>

#define IMG_H  384
#define IMG_W  384
#define IMG_HW (IMG_H * IMG_W)
#define NB     4
#define NC     3
#define NK     48
#define NH     24          /* taps per lane-half */

typedef float f4  __attribute__((ext_vector_type(4)));              /* 16B-aligned */
typedef float f4u __attribute__((ext_vector_type(4), aligned(4)));  /* unaligned ld */

struct PosAdd { float v[NK]; };

__device__ __forceinline__ f4 ld4(const float* __restrict__ p) {
    return (f4)(*(const f4u* __restrict__)p);
}

/* left tap: columns w0+i-d, clamped at 0 */
__device__ __forceinline__ f4 ldL(const float* __restrict__ rowp, int w0, int d) {
    if (w0 >= d) return ld4(rowp + (w0 - d));
    f4 r;
#pragma unroll
    for (int i = 0; i < 4; ++i) r[i] = rowp[max(w0 + i - d, 0)];
    return r;
}

/* right tap: columns w0+i+d, clamped at W-1 */
__device__ __forceinline__ f4 ldR(const float* __restrict__ rowp, int w0, int d) {
    if (w0 + d <= IMG_W - 4) return ld4(rowp + (w0 + d));
    f4 r;
#pragma unroll
    for (int i = 0; i < 4; ++i) r[i] = rowp[min(w0 + i + d, IMG_W - 1)];
    return r;
}

__device__ __forceinline__ f4 min4(f4 a, f4 b) {
    f4 r;
#pragma unroll
    for (int i = 0; i < 4; ++i) r[i] = fminf(a[i], b[i]);
    return r;
}

__device__ __forceinline__ f4 exp2_4(f4 v) {
    f4 r;
#pragma unroll
    for (int i = 0; i < 4; ++i) r[i] = __builtin_amdgcn_exp2f(v[i]);
    return r;
}

__global__ __launch_bounds__(256) void LLA_41412074668179_kernel(
    const float* __restrict__ imgs, float* __restrict__ out, PosAdd pa)
{
    const int tid  = threadIdx.x;
    const int lane = tid & 63;
    const int t    = lane >> 5;              // 0 -> dil{1,2,4}=k0..23, 1 -> dil{8,12,24}=k24..47

    // XCD-chunked swizzle: 1152 blocks = 8 XCDs x 144; keep +/-24-row reuse in one XCD's L2.
    const int lb = (blockIdx.x & 7) * 144 + (blockIdx.x >> 3);

    // 4 consecutive pixels per thread; half-wave (32 lanes) covers 128 consecutive
    // pixels; both halves same pixels. 128*(4lb+warp) % 384 in {0,128,256}
    // => a wave never straddles a row; thread's 4 px share one row (384 % 4 == 0).
    const int px0 = lb * 512 + (tid >> 6) * 128 + (lane & 31) * 4;
    const int w0 = px0 % IMG_W;
    const int hb = px0 / IMG_W;
    const int h  = hb % IMG_H;
    const int b  = hb / IMG_H;

    const int dils[3] = { t ? 8 : 1, t ? 12 : 2, t ? 24 : 4 };

    const int r0 = h * IMG_W;
    int rm[3], rp[3];
#pragma unroll
    for (int di = 0; di < 3; ++di) {
        const int d = dils[di];
        rm[di] = max(h - d, 0) * IMG_W;
        rp[di] = min(h + d, IMG_H - 1) * IMG_W;
    }

    f4 acc[NH];
#pragma unroll
    for (int j = 0; j < NH; ++j) acc[j] = (f4){0.0f, 0.0f, 0.0f, 0.0f};

#pragma unroll
    for (int c = 0; c < NC; ++c) {
        const float* __restrict__ pc = imgs + ((size_t)b * NC + c) * IMG_HW;
        const f4 x = ld4(pc + r0 + w0);

        f4 nbv[NH];
#pragma unroll
        for (int di = 0; di < 3; ++di) {
            const int d = dils[di];
            const float* __restrict__ pm = pc + rm[di];
            const float* __restrict__ p0 = pc + r0;
            const float* __restrict__ pp = pc + rp[di];
            nbv[di*8+0] = ldL(pm, w0, d);
            nbv[di*8+1] = ld4(pm + w0);
            nbv[di*8+2] = ldR(pm, w0, d);
            nbv[di*8+3] = ldL(p0, w0, d);
            nbv[di*8+4] = ldR(p0, w0, d);
            nbv[di*8+5] = ldL(pp, w0, d);
            nbv[di*8+6] = ld4(pp + w0);
            nbv[di*8+7] = ldR(pp, w0, d);
        }

        // partial stats over my 24 taps (per pixel component); combine halves -> 48
        f4 s0 = (f4){0,0,0,0}, s1 = (f4){0,0,0,0};
        f4 q0 = (f4){0,0,0,0}, q1 = (f4){0,0,0,0};
#pragma unroll
        for (int j = 0; j < NH; j += 2) {
            s0 += nbv[j];
            s1 += nbv[j+1];
            q0 += nbv[j]   * nbv[j];
            q1 += nbv[j+1] * nbv[j+1];
        }
        f4 s  = s0 + s1;
        f4 ss = q0 + q1;
#pragma unroll
        for (int i = 0; i < 4; ++i) {
            s[i]  += __shfl_xor(s[i],  32);
            ss[i] += __shfl_xor(ss[i], 32);
        }

        f4 scl;
#pragma unroll
        for (int i = 0; i < 4; ++i) {
            const float mean = s[i] * (1.0f / 48.0f);
            const float var  = fmaxf((ss[i] - s[i] * mean) * (1.0f / 47.0f), 0.0f);
            scl[i] = __builtin_amdgcn_rcpf(
                         fmaf(__builtin_amdgcn_sqrtf(var), 0.3f, 3.0e-9f));
        }
        const f4 xs = x * scl;

#pragma unroll
        for (int j = 0; j < NH; ++j) {
            const f4 dd = nbv[j] * scl - xs;   // fused per component
            acc[j] += dd * dd;
        }
    }

    // softmax over all 48: max(aff) == min(acc); cross-half via shfl
    f4 m0 = min4(acc[0], acc[1]), m1 = min4(acc[2], acc[3]);
    f4 m2 = min4(acc[4], acc[5]), m3 = min4(acc[6], acc[7]);
#pragma unroll
    for (int j = 8; j < NH; j += 8) {
        m0 = min4(m0, min4(acc[j+0], acc[j+1]));
        m1 = min4(m1, min4(acc[j+2], acc[j+3]));
        m2 = min4(m2, min4(acc[j+4], acc[j+5]));
        m3 = min4(m3, min4(acc[j+6], acc[j+7]));
    }
    f4 mn = min4(min4(m0, m1), min4(m2, m3));
#pragma unroll
    for (int i = 0; i < 4; ++i)
        mn[i] = fminf(mn[i], __shfl_xor(mn[i], 32));

    const float SC   = (1.0f / 3.0f) * 1.44269504f;   // /3 then ln->log2
    const f4 mnSC = mn * SC;
    f4 e0 = (f4){0,0,0,0}, e1 = (f4){0,0,0,0};
    f4 e2 = (f4){0,0,0,0}, e3 = (f4){0,0,0,0};
#pragma unroll
    for (int j = 0; j < NH; j += 4) {
        acc[j+0] = exp2_4(acc[j+0] * -SC + mnSC);
        acc[j+1] = exp2_4(acc[j+1] * -SC + mnSC);
        acc[j+2] = exp2_4(acc[j+2] * -SC + mnSC);
        acc[j+3] = exp2_4(acc[j+3] * -SC + mnSC);
        e0 += acc[j+0]; e1 += acc[j+1]; e2 += acc[j+2]; e3 += acc[j+3];
    }
    f4 se = (e0 + e1) + (e2 + e3);
#pragma unroll
    for (int i = 0; i < 4; ++i)
        se[i] += __shfl_xor(se[i], 32);
    f4 inv;
#pragma unroll
    for (int i = 0; i < 4; ++i)
        inv[i] = __builtin_amdgcn_rcpf(se[i]);

    float* __restrict__ op = out + ((size_t)(b * NK + t * NH)) * IMG_HW + r0 + w0;
#pragma unroll
    for (int j = 0; j < NH; ++j) {
        const float pav = t ? pa.v[NH + j] : pa.v[j];
        const f4 v = acc[j] * inv + pav;
        __builtin_nontemporal_store(v, (f4*)(op + (size_t)j * IMG_HW));
    }
}

static void compute_pos_add(float* out48)
{
    const int DIL[6] = {1, 2, 4, 8, 12, 24};
    const double SQ2 = 1.4142135623730951;
    const double diag[8] = {SQ2, 1.0, SQ2, 1.0, 1.0, SQ2, 1.0, SQ2};

    double pos[NK];
    for (int di = 0; di < 6; ++di)
        for (int tp = 0; tp < 8; ++tp)
            pos[di * 8 + tp] = (double)((float)(diag[tp] * DIL[di]));  // match fp32 concat

    double s = 0.0;
    for (int k = 0; k < NK; ++k) s += pos[k];
    const double m = s / NK;
    double v = 0.0;
    for (int k = 0; k < NK; ++k) { const double d = pos[k] - m; v += d * d; }
    v /= (NK - 1);
    const double stdv = sqrt(v);

    double aff[NK];
    double mx = -1e300;
    for (int k = 0; k < NK; ++k) {
        const double q = pos[k] / ((stdv + 1e-8) * 0.3);
        aff[k] = -(q * q);
        if (aff[k] > mx) mx = aff[k];
    }
    double se = 0.0;
    for (int k = 0; k < NK; ++k) { aff[k] = exp(aff[k] - mx); se += aff[k]; }
    for (int k = 0; k < NK; ++k) out48[k] = (float)(0.01 * aff[k] / se);
}

extern "C" void kernel_launch(void* const* d_in, const int* in_sizes, int n_in,
                              void* d_out, int out_size, void* d_ws, size_t ws_size,
                              hipStream_t stream)
{
    const float* imgs = (const float*)d_in[0];
    float* out = (float*)d_out;

    PosAdd pa;
    compute_pos_add(pa.v);

    // 2 thread-slots per pixel (k-split across lane halves), 4 pixels per thread
    const int blocks = (NB * IMG_H * IMG_W * 2) / (256 * 4);   // 1152
    LLA_41412074668179_kernel<<<blocks, 256, 0, stream>>>(imgs, out, pa);
}